// Round 12
// baseline (583.934 us; speedup 1.0000x reference)
//
#include <hip/hip_runtime.h>
#include <math.h>

#define DIM 2048
#define NROWS 4096            // B*S
#define WN (DIM*DIM)
#define HEADS 16
#define HDIM 128
#define SEQ 2048

typedef __attribute__((ext_vector_type(8))) short short8;
typedef __attribute__((ext_vector_type(8))) _Float16 half8;
typedef __attribute__((ext_vector_type(4))) float floatx4;
typedef __attribute__((ext_vector_type(4))) int intx4;

__device__ __forceinline__ unsigned short f2h(float f) {
  _Float16 h = (_Float16)f;
  return __builtin_bit_cast(unsigned short, h);
}
__device__ __forceinline__ float h2f(unsigned short u) {
  _Float16 h = __builtin_bit_cast(_Float16, u);
  return (float)h;
}
// packed f32x2 -> f16x2 (RTZ) as a single u32
__device__ __forceinline__ unsigned pkh2(float a, float b) {
  return __builtin_bit_cast(unsigned, __builtin_amdgcn_cvt_pkrtz(a, b));
}

// async global->LDS, 16B per lane; lds base must be wave-uniform (HW scatters lane i at +i*16)
__device__ __forceinline__ void gload_lds16(const void* g, void* l) {
  __builtin_amdgcn_global_load_lds(
      (const __attribute__((address_space(1))) unsigned int*)g,
      (__attribute__((address_space(3))) unsigned int*)l, 16, 0, 0);
}

__device__ __forceinline__ float wredSum(float v) {
  #pragma unroll
  for (int o = 1; o < 64; o <<= 1) v += __shfl_xor(v, o);
  return v;
}
__device__ __forceinline__ float wredMax(float v) {
  #pragma unroll
  for (int o = 1; o < 64; o <<= 1) v = fmaxf(v, __shfl_xor(v, o));
  return v;
}

__device__ __forceinline__ float blockReduceSum(float v, float* red) {
  int tid = threadIdx.x;
  red[tid] = v; __syncthreads();
  for (int s = 128; s > 0; s >>= 1) {
    if (tid < s) red[tid] += red[tid + s];
    __syncthreads();
  }
  float r = red[0]; __syncthreads();
  return r;
}

__device__ __forceinline__ const float* pick_w(const float* a, const float* b,
                                               const float* c, const float* d, int i) {
  return i == 0 ? a : i == 1 ? b : i == 2 ? c : d;
}

// ---------------- weight stats ----------------
__global__ __launch_bounds__(256) void w_abs_partial(
    const float* w0, const float* w1, const float* w2, const float* w3, float* part)
{
  const float4* w4 = (const float4*)pick_w(w0, w1, w2, w3, blockIdx.y);
  float s = 0.f;
  for (int i = blockIdx.x * 256 + threadIdx.x; i < WN / 4; i += 1024 * 256) {
    float4 v = w4[i];
    s += fabsf(v.x) + fabsf(v.y) + fabsf(v.z) + fabsf(v.w);
  }
  __shared__ float red[256];
  float t = blockReduceSum(s, red);
  if (threadIdx.x == 0) part[blockIdx.y * 1024 + blockIdx.x] = t;
}

__global__ __launch_bounds__(256) void w_delta_final(const float* part, float* stats)
{
  float s = 0.f;
  for (int i = threadIdx.x; i < 1024; i += 256) s += part[blockIdx.x * 1024 + i];
  __shared__ float red[256];
  float t = blockReduceSum(s, red);
  if (threadIdx.x == 0) stats[blockIdx.x] = 0.7f * (t / (float)WN);
}

__device__ __forceinline__ signed char tq(float v, float delta) {
  if (fabsf(v) > delta) return (v > 0.f) ? (signed char)1 : (signed char)-1;
  return (signed char)0;
}

// fused: ternary-quantize weights (int8 {-1,0,1}) AND accumulate alpha partials
__global__ __launch_bounds__(256) void w_maskquant(
    const float* w0, const float* w1, const float* w2, const float* w3,
    const float* stats, float* part2, signed char* tern)
{
  int wi = blockIdx.y;
  const float4* w4 = (const float4*)pick_w(w0, w1, w2, w3, wi);
  float delta = stats[wi];
  char4* out = (char4*)(tern + (size_t)wi * WN);
  float s = 0.f, cnt = 0.f;
  for (int i = blockIdx.x * 256 + threadIdx.x; i < WN / 4; i += 1024 * 256) {
    float4 v = w4[i];
    char4 o;
    float a;
    a = fabsf(v.x); if (a > delta) { s += a; cnt += 1.f; } o.x = tq(v.x, delta);
    a = fabsf(v.y); if (a > delta) { s += a; cnt += 1.f; } o.y = tq(v.y, delta);
    a = fabsf(v.z); if (a > delta) { s += a; cnt += 1.f; } o.z = tq(v.z, delta);
    a = fabsf(v.w); if (a > delta) { s += a; cnt += 1.f; } o.w = tq(v.w, delta);
    out[i] = o;
  }
  __shared__ float red[256];
  float ts = blockReduceSum(s, red);
  float tc = blockReduceSum(cnt, red);
  if (threadIdx.x == 0) {
    part2[((size_t)blockIdx.y * 1024 + blockIdx.x) * 2]     = ts;
    part2[((size_t)blockIdx.y * 1024 + blockIdx.x) * 2 + 1] = tc;
  }
}

__global__ __launch_bounds__(256) void w_alpha_final(const float* part2, float* stats)
{
  float s = 0.f, c = 0.f;
  for (int i = threadIdx.x; i < 1024; i += 256) {
    s += part2[((size_t)blockIdx.x * 1024 + i) * 2];
    c += part2[((size_t)blockIdx.x * 1024 + i) * 2 + 1];
  }
  __shared__ float red[256];
  float ts = blockReduceSum(s, red);
  float tc = blockReduceSum(c, red);
  if (threadIdx.x == 0) stats[4 + blockIdx.x] = ts / fmaxf(tc, 1.f);
}

// ---------------- LN kernels: one WAVE per row, shuffle-only reductions, no atomics --------
__global__ __launch_bounds__(256) void ln_absmax3(
    const float* __restrict__ x,
    const float* __restrict__ g0, const float* __restrict__ b0,
    const float* __restrict__ g1, const float* __restrict__ b1,
    const float* __restrict__ g2, const float* __restrict__ b2,
    float* __restrict__ pmax)     // [3][NROWS] per-row maxima
{
  const int lane = threadIdx.x & 63;
  const int row = blockIdx.x * 4 + (threadIdx.x >> 6);
  const float* xr = x + (size_t)row * DIM;
  float4 a[8];
  float s = 0.f, sq = 0.f;
  #pragma unroll
  for (int j = 0; j < 8; ++j) {
    a[j] = *(const float4*)(xr + j * 256 + lane * 4);
    s  += a[j].x + a[j].y + a[j].z + a[j].w;
    sq += a[j].x*a[j].x + a[j].y*a[j].y + a[j].z*a[j].z + a[j].w*a[j].w;
  }
  s = wredSum(s); sq = wredSum(sq);
  float mu = s * (1.f / DIM);
  float var = sq * (1.f / DIM) - mu * mu;
  float rstd = 1.f / sqrtf(var + 1e-5f);
  const float* gs[3] = {g0, g1, g2};
  const float* bs[3] = {b0, b1, b2};
  #pragma unroll
  for (int p = 0; p < 3; ++p) {
    float m = 0.f;
    #pragma unroll
    for (int j = 0; j < 8; ++j) {
      float4 gg = *(const float4*)(gs[p] + j * 256 + lane * 4);
      float4 bb = *(const float4*)(bs[p] + j * 256 + lane * 4);
      m = fmaxf(m, fabsf((a[j].x - mu) * rstd * gg.x + bb.x));
      m = fmaxf(m, fabsf((a[j].y - mu) * rstd * gg.y + bb.y));
      m = fmaxf(m, fabsf((a[j].z - mu) * rstd * gg.z + bb.z));
      m = fmaxf(m, fabsf((a[j].w - mu) * rstd * gg.w + bb.w));
    }
    m = wredMax(m);
    if (lane == 0) pmax[(size_t)p * NROWS + row] = m;
  }
}

// one block per projection: reduce NROWS partial maxima -> ambits[p] (direct write, no atomic)
__global__ __launch_bounds__(256) void absmax_final(
    const float* __restrict__ pmax, unsigned* __restrict__ ambits)
{
  const float* src = pmax + (size_t)blockIdx.x * NROWS;
  float m = 0.f;
  for (int i = threadIdx.x; i < NROWS; i += 256) m = fmaxf(m, src[i]);
  m = wredMax(m);
  __shared__ float red[4];
  if ((threadIdx.x & 63) == 0) red[threadIdx.x >> 6] = m;
  __syncthreads();
  if (threadIdx.x == 0)
    ambits[blockIdx.x] = __float_as_uint(fmaxf(fmaxf(red[0], red[1]), fmaxf(red[2], red[3])));
}

__global__ __launch_bounds__(256) void ln_quant3(
    const float* __restrict__ x,
    const float* __restrict__ g0, const float* __restrict__ b0,
    const float* __restrict__ g1, const float* __restrict__ b1,
    const float* __restrict__ g2, const float* __restrict__ b2,
    const unsigned* __restrict__ ambits,
    signed char* __restrict__ xq0, signed char* __restrict__ xq1,
    signed char* __restrict__ xq2)
{
  const int lane = threadIdx.x & 63;
  const int row = blockIdx.x * 4 + (threadIdx.x >> 6);
  const float* xr = x + (size_t)row * DIM;
  float4 a[8];
  float s = 0.f, sq = 0.f;
  #pragma unroll
  for (int j = 0; j < 8; ++j) {
    a[j] = *(const float4*)(xr + j * 256 + lane * 4);
    s  += a[j].x + a[j].y + a[j].z + a[j].w;
    sq += a[j].x*a[j].x + a[j].y*a[j].y + a[j].z*a[j].z + a[j].w*a[j].w;
  }
  s = wredSum(s); sq = wredSum(sq);
  float mu = s * (1.f / DIM);
  float var = sq * (1.f / DIM) - mu * mu;
  float rstd = 1.f / sqrtf(var + 1e-5f);
  const float* gs[3] = {g0, g1, g2};
  const float* bs[3] = {b0, b1, b2};
  signed char* outs[3] = {xq0, xq1, xq2};
  #pragma unroll
  for (int p = 0; p < 3; ++p) {
    float sc = 127.f / fmaxf(__uint_as_float(ambits[p]), 1e-5f);
    #pragma unroll
    for (int j = 0; j < 8; ++j) {
      float4 gg = *(const float4*)(gs[p] + j * 256 + lane * 4);
      float4 bb = *(const float4*)(bs[p] + j * 256 + lane * 4);
      float y0 = (a[j].x - mu) * rstd * gg.x + bb.x;
      float y1 = (a[j].y - mu) * rstd * gg.y + bb.y;
      float y2 = (a[j].z - mu) * rstd * gg.z + bb.z;
      float y3 = (a[j].w - mu) * rstd * gg.w + bb.w;
      char4 q;
      q.x = (signed char)(int)fminf(fmaxf(rintf(y0 * sc), -128.f), 127.f);
      q.y = (signed char)(int)fminf(fmaxf(rintf(y1 * sc), -128.f), 127.f);
      q.z = (signed char)(int)fminf(fmaxf(rintf(y2 * sc), -128.f), 127.f);
      q.w = (signed char)(int)fminf(fmaxf(rintf(y3 * sc), -128.f), 127.f);
      *(char4*)(outs[p] + (size_t)row * DIM + j * 256 + lane * 4) = q;
    }
  }
}

// ---------------- o-projection LN over MERGED flash partials, wave-per-row ----------------
// po0/po1: fp16 normalized partial O halves; lm: [2][NROWS][HEADS] logsumexp.
// merged v = (2^(L1-Lm)*v1 + 2^(L2-Lm)*v2) / (2^(L1-Lm)+2^(L2-Lm)) per (row, head).
// MODE 0: per-row absmax -> pmax. MODE 1: quantize with ambits.
template<int MODE>
__global__ __launch_bounds__(256) void ln_kernel(
    const unsigned short* __restrict__ po0, const unsigned short* __restrict__ po1,
    const float* __restrict__ lm,
    const float* __restrict__ g, const float* __restrict__ bias,
    const unsigned* __restrict__ ambits, float* __restrict__ pmax,
    signed char* __restrict__ xq)
{
  const int lane = threadIdx.x & 63;
  const int row = blockIdx.x * 4 + (threadIdx.x >> 6);
  float4 a[8];
  float s = 0.f, sq = 0.f;
  #pragma unroll
  for (int j = 0; j < 8; ++j) {
    int h_e = j * 2 + (lane >> 5);
    float L1 = lm[(size_t)row * HEADS + h_e];
    float L2 = lm[(size_t)NROWS * HEADS + (size_t)row * HEADS + h_e];
    float Lm = fmaxf(L1, L2);
    float wa = exp2f(L1 - Lm), wb = exp2f(L2 - Lm);
    float rs = 1.f / (wa + wb);
    wa *= rs; wb *= rs;
    ushort4 u1 = *(const ushort4*)(po0 + (size_t)row * DIM + j * 256 + lane * 4);
    ushort4 u2 = *(const ushort4*)(po1 + (size_t)row * DIM + j * 256 + lane * 4);
    a[j].x = wa * h2f(u1.x) + wb * h2f(u2.x);
    a[j].y = wa * h2f(u1.y) + wb * h2f(u2.y);
    a[j].z = wa * h2f(u1.z) + wb * h2f(u2.z);
    a[j].w = wa * h2f(u1.w) + wb * h2f(u2.w);
    s  += a[j].x + a[j].y + a[j].z + a[j].w;
    sq += a[j].x*a[j].x + a[j].y*a[j].y + a[j].z*a[j].z + a[j].w*a[j].w;
  }
  s = wredSum(s); sq = wredSum(sq);
  float mu = s * (1.f / DIM);
  float var = sq * (1.f / DIM) - mu * mu;
  float rstd = 1.f / sqrtf(var + 1e-5f);
  if (MODE == 0) {
    float m = 0.f;
    #pragma unroll
    for (int j = 0; j < 8; ++j) {
      float4 gg = *(const float4*)(g + j * 256 + lane * 4);
      float4 bb = *(const float4*)(bias + j * 256 + lane * 4);
      m = fmaxf(m, fabsf((a[j].x - mu) * rstd * gg.x + bb.x));
      m = fmaxf(m, fabsf((a[j].y - mu) * rstd * gg.y + bb.y));
      m = fmaxf(m, fabsf((a[j].z - mu) * rstd * gg.z + bb.z));
      m = fmaxf(m, fabsf((a[j].w - mu) * rstd * gg.w + bb.w));
    }
    m = wredMax(m);
    if (lane == 0) pmax[row] = m;
  } else {
    float sc = 127.f / fmaxf(__uint_as_float(*ambits), 1e-5f);
    #pragma unroll
    for (int j = 0; j < 8; ++j) {
      float4 gg = *(const float4*)(g + j * 256 + lane * 4);
      float4 bb = *(const float4*)(bias + j * 256 + lane * 4);
      float y0 = (a[j].x - mu) * rstd * gg.x + bb.x;
      float y1 = (a[j].y - mu) * rstd * gg.y + bb.y;
      float y2 = (a[j].z - mu) * rstd * gg.z + bb.z;
      float y3 = (a[j].w - mu) * rstd * gg.w + bb.w;
      char4 q;
      q.x = (signed char)(int)fminf(fmaxf(rintf(y0 * sc), -128.f), 127.f);
      q.y = (signed char)(int)fminf(fmaxf(rintf(y1 * sc), -128.f), 127.f);
      q.z = (signed char)(int)fminf(fmaxf(rintf(y2 * sc), -128.f), 127.f);
      q.w = (signed char)(int)fminf(fmaxf(rintf(y3 * sc), -128.f), 127.f);
      *(char4*)(xq + (size_t)row * DIM + j * 256 + lane * 4) = q;
    }
  }
}

// ---------------- merged QKV int8 GEMM (z = projection), m97 structure ----------------
// z==0/1: fp16 C store with FUSED RoPE (angle = head * inv[p]; q also scaled by
// (1/sqrt(128))*log2(e)). z==2: transposed fp16 epilogue via LDS -> vt layout.
__global__ __launch_bounds__(256) void gemm_qkv(
    const signed char* __restrict__ A0, const signed char* __restrict__ A1,
    const signed char* __restrict__ A2, const signed char* __restrict__ Bt0,
    unsigned short* __restrict__ C0, unsigned short* __restrict__ C1,
    unsigned short* __restrict__ C2t, const float* __restrict__ stats)
{
  const int tid = threadIdx.x;
  const int lane = tid & 63;
  const int w = tid >> 6;
  const int wm = w >> 1, wn = w & 1;
  const int quad = lane >> 4, l16 = lane & 15;
  const int bm = blockIdx.x * 128, bn = blockIdx.y * 128;
  const int z = blockIdx.z;

  const signed char* A  = z == 0 ? A0 : z == 1 ? A1 : A2;
  const signed char* Bt = Bt0 + (size_t)z * WN;

  // single 32 KB staging buffer (As | Bs); reused by the transposed epilogue for z==2
  __shared__ __align__(16) signed char smem[2 * 128 * 128];
  signed char* As = smem;
  signed char* Bs = smem + 128 * 128;

  const int srow_off = lane >> 3;        // 0..7
  const int scol     = (lane & 7) * 16;  // bytes

  intx4 acc[4][4];
  #pragma unroll
  for (int i = 0; i < 4; ++i)
    #pragma unroll
    for (int j = 0; j < 4; ++j) acc[i][j] = {0, 0, 0, 0};

  for (int k0 = 0; k0 < DIM; k0 += 128) {
    #pragma unroll
    for (int i = 0; i < 4; ++i) {
      int c = i * 4 + w;                 // wave-uniform chunk id, 16 chunks = 128 rows
      int row = c * 8 + srow_off;
      gload_lds16(A  + (size_t)(bm + row) * DIM + k0 + scol, &As[c * 1024]);
      gload_lds16(Bt + (size_t)(bn + row) * DIM + k0 + scol, &Bs[c * 1024]);
    }
    __syncthreads();
    #pragma unroll
    for (int kc = 0; kc < 2; ++kc) {
      intx4 af[4], bf[4];
      #pragma unroll
      for (int i = 0; i < 4; ++i)
        af[i] = *(const intx4*)&As[(wm * 64 + i * 16 + l16) * 128 + kc * 64 + quad * 16];
      #pragma unroll
      for (int j = 0; j < 4; ++j)
        bf[j] = *(const intx4*)&Bs[(wn * 64 + j * 16 + l16) * 128 + kc * 64 + quad * 16];
      #pragma unroll
      for (int i = 0; i < 4; ++i)
        #pragma unroll
        for (int j = 0; j < 4; ++j)
          acc[i][j] = __builtin_amdgcn_mfma_i32_16x16x64_i8(af[i], bf[j], acc[i][j], 0, 0, 0);
    }
    __syncthreads();
  }

  const unsigned* am = (const unsigned*)(stats + 8);
  float scale = stats[4 + z] * fmaxf(__uint_as_float(am[z]), 1e-5f) * (1.f / 127.f);

  if (z < 2) {
    // fused RoPE: head h = blockIdx.y; pair p = d>>1, d = wn*64 + j*16 + l16.
    // even d: v' = v*cs - pv*sn ; odd d: v' = pv*sn + v*cs (pv = partner via shfl_xor 1).
    // q (z==0) folds SC = (1/sqrt(128))*log2(e) into cs/sn.
    const float SC = 0.12751741769011063f;
    const int hh = blockIdx.y;
    const int odd = l16 & 1;
    float cs[4], sn[4];
    #pragma unroll
    for (int j = 0; j < 4; ++j) {
      int p = (wn * 64 + j * 16 + l16) >> 1;
      float inv = exp2f((float)p * -0.20762050593046f);  // 10000^(-p/64)
      float ang = (float)hh * inv;
      float ss, cc;
      __sincosf(ang, &ss, &cc);
      if (z == 0) { ss *= SC; cc *= SC; }
      cs[j] = cc; sn[j] = ss;
    }
    unsigned short* Cp = z == 0 ? C0 : C1;
    #pragma unroll
    for (int i = 0; i < 4; ++i)
      #pragma unroll
      for (int j = 0; j < 4; ++j)
        #pragma unroll
        for (int r = 0; r < 4; ++r) {
          int m = bm + wm * 64 + i * 16 + quad * 4 + r;
          int n = bn + wn * 64 + j * 16 + l16;
          float v = (float)acc[i][j][r] * scale;
          float pv = __shfl_xor(v, 1);
          float out = odd ? (pv * sn[j] + v * cs[j]) : (v * cs[j] - pv * sn[j]);
          Cp[(size_t)m * DIM + n] = f2h(out);
        }
  } else {
    // transposed epilogue: smem := tileT[d][s] fp16, XOR-swizzled; then coalesced store
    #pragma unroll
    for (int i = 0; i < 4; ++i)
      #pragma unroll
      for (int j = 0; j < 4; ++j)
        #pragma unroll
        for (int r = 0; r < 4; ++r) {
          int s = wm * 64 + i * 16 + quad * 4 + r;   // local m (= seq)
          int d = wn * 64 + j * 16 + l16;            // local n (= head dim)
          int byte = (d * 256 + s * 2) ^ ((d & 7) << 4);
          *(unsigned short*)(smem + byte) = f2h((float)acc[i][j][r] * scale);
        }
    __syncthreads();
    const int b = bm >> 11;                // batch (SEQ = 2048 rows per batch)
    const int s_base = bm & (SEQ - 1);
    const int h = blockIdx.y;              // bn covers exactly one head (128 cols)
    const int sc = (tid & 15) * 8;         // halves within a d-row
    #pragma unroll
    for (int pass = 0; pass < 8; ++pass) {
      int d = (tid >> 4) + pass * 16;
      int byte = (d * 256 + sc * 2) ^ ((d & 7) << 4);
      *(uint4*)(C2t + ((size_t)(b * HEADS + h) * HDIM + d) * SEQ + s_base + sc) =
          *(const uint4*)(smem + byte);
    }
  }
}

// ---------------- O-projection int8 GEMM (fp32 out), m97 structure ----------------
__global__ __launch_bounds__(256) void gemm_bt(
    const signed char* __restrict__ A, const signed char* __restrict__ Bt,
    float* __restrict__ Cp, const float* __restrict__ stats, int wi)
{
  const int tid = threadIdx.x;
  const int lane = tid & 63;
  const int w = tid >> 6;
  const int wm = w >> 1, wn = w & 1;
  const int quad = lane >> 4, l16 = lane & 15;
  const int bm = blockIdx.x * 128, bn = blockIdx.y * 128;

  __shared__ __align__(16) signed char As[128 * 128];
  __shared__ __align__(16) signed char Bs[128 * 128];

  const int srow_off = lane >> 3;
  const int scol     = (lane & 7) * 16;

  intx4 acc[4][4];
  #pragma unroll
  for (int i = 0; i < 4; ++i)
    #pragma unroll
    for (int j = 0; j < 4; ++j) acc[i][j] = {0, 0, 0, 0};

  for (int k0 = 0; k0 < DIM; k0 += 128) {
    #pragma unroll
    for (int i = 0; i < 4; ++i) {
      int c = i * 4 + w;
      int row = c * 8 + srow_off;
      gload_lds16(A  + (size_t)(bm + row) * DIM + k0 + scol, &As[c * 1024]);
      gload_lds16(Bt + (size_t)(bn + row) * DIM + k0 + scol, &Bs[c * 1024]);
    }
    __syncthreads();
    #pragma unroll
    for (int kc = 0; kc < 2; ++kc) {
      intx4 af[4], bf[4];
      #pragma unroll
      for (int i = 0; i < 4; ++i)
        af[i] = *(const intx4*)&As[(wm * 64 + i * 16 + l16) * 128 + kc * 64 + quad * 16];
      #pragma unroll
      for (int j = 0; j < 4; ++j)
        bf[j] = *(const intx4*)&Bs[(wn * 64 + j * 16 + l16) * 128 + kc * 64 + quad * 16];
      #pragma unroll
      for (int i = 0; i < 4; ++i)
        #pragma unroll
        for (int j = 0; j < 4; ++j)
          acc[i][j] = __builtin_amdgcn_mfma_i32_16x16x64_i8(af[i], bf[j], acc[i][j], 0, 0, 0);
    }
    __syncthreads();
  }

  const unsigned* am = (const unsigned*)(stats + 8);
  float scale = stats[4 + wi] * fmaxf(__uint_as_float(am[wi]), 1e-5f) * (1.f / 127.f);
  #pragma unroll
  for (int i = 0; i < 4; ++i)
    #pragma unroll
    for (int j = 0; j < 4; ++j)
      #pragma unroll
      for (int r = 0; r < 4; ++r) {
        int m = bm + wm * 64 + i * 16 + quad * 4 + r;
        int n = bn + wn * 64 + j * 16 + l16;
        Cp[(size_t)m * DIM + n] = (float)acc[i][j][r] * scale;
      }
}

// ---------------- flash attention: QBLK=128, KV-split=2, gload_lds staging ----------------
// Q pre-scaled by (1/sqrt(128))*log2(e); softmax in exp2 domain; T13 defer-rescale.
// Grid 1024 = (16 qt x 2 kv-halves) x 32 bh; LDS 48KB -> 3 blocks/CU (was grid-capped at 2).
// Each block covers 16 K-tiles; emits fp16 NORMALIZED partial O + logsumexp L = m + log2(l);
// the o-projection LN kernels merge the two halves on the fly.
// XCD-chunked remap: id%8 = XCD, 4 bh/XCD (K/V panels fit the 4MB private L2).
__global__ __launch_bounds__(256, 3) void flash_attn(
    const unsigned short* __restrict__ qf, const unsigned short* __restrict__ kf,
    const unsigned short* __restrict__ vt,
    unsigned short* __restrict__ po0, unsigned short* __restrict__ po1,
    float* __restrict__ lm)
{
  const int tid = threadIdx.x;
  const int lane = tid & 63;
  const int w = tid >> 6;
  const int quad = lane >> 4;
  const int l16 = lane & 15;
  // decode: xcd = id&7, slot = id>>3; bh = xcd*4 + slot/32; rem = slot%32; qt = rem/2, half = rem&1
  const int L = blockIdx.x;
  const int slot = L >> 3;
  const int bh = ((L & 7) << 2) | (slot >> 5);
  const int rem = slot & 31;
  const int qt = rem >> 1;
  const int half = rem & 1;
  const int b = bh >> 4;
  const int h = bh & 15;

  __shared__ __align__(16) char Ks[64 * 256];     // [key t][d] halves; swizzled via source
  __shared__ __align__(16) char Vs[128 * 128];    // [d][t] halves;    swizzled via source
  __shared__ __align__(16) char Ps[4][32 * 128];  // per-wave [q 0..31][t] halves, swizzled

  // Q fragments (B-operand): wave owns 32 q-rows, two 16-row fragments
  const size_t qbase = ((size_t)(b * SEQ + qt * 128 + w * 32 + l16)) * DIM + h * HDIM;
  short8 qa[2][4];
  #pragma unroll
  for (int f = 0; f < 2; ++f)
    #pragma unroll
    for (int kc = 0; kc < 4; ++kc)
      qa[f][kc] = *(const short8*)(qf + qbase + (size_t)f * 16 * DIM + kc * 32 + quad * 8);

  float m_q[2] = {-INFINITY, -INFINITY};
  float l_q[2] = {0.f, 0.f};
  floatx4 accO0[8], accO1[8];           // O^T: rows d=dt*16+quad*4+r, col q = f*16+l16
  #pragma unroll
  for (int i = 0; i < 8; ++i) { accO0[i] = {0.f, 0.f, 0.f, 0.f}; accO1[i] = {0.f, 0.f, 0.f, 0.f}; }

  const char* kg = (const char*)(kf + (size_t)(b * SEQ) * DIM + h * HDIM);
  const char* vg = (const char*)(vt + (size_t)bh * HDIM * SEQ);

  // per-lane pre-swizzled source offsets (bytes) for this wave's 4 chunks of K and V.
  int koff[4], voff[4];
  #pragma unroll
  for (int j = 0; j < 4; ++j) {
    int c = w * 4 + j;
    int rK = c * 4 + (lane >> 4);
    koff[j] = rK * (DIM * 2) + (((lane & 15) * 16) ^ ((rK & 7) << 4));
    int rV = c * 8 + (lane >> 3);
    voff[j] = rV * (SEQ * 2) + (((lane & 7) * 16) ^ ((rV & 7) << 4));
  }

  for (int kt = half * 16; kt < half * 16 + 16; ++kt) {
    __syncthreads();                    // prior tile's LDS reads complete
    const char* kgb = kg + (size_t)kt * 64 * DIM * 2;   // key rows advance
    const char* vgb = vg + (size_t)kt * 128;            // value cols advance (bytes)
    #pragma unroll
    for (int j = 0; j < 4; ++j) {
      int c = w * 4 + j;
      gload_lds16(kgb + koff[j], &Ks[c * 1024]);
      gload_lds16(vgb + voff[j], &Vs[c * 1024]);
    }
    asm volatile("s_waitcnt vmcnt(0)" ::: "memory");
    __syncthreads();

    // S^T = K Q'^T : lane q = f*16+l16, keys t = jt*16 + quad*4 + r
    float sreg[2][4][4];
    __builtin_amdgcn_s_setprio(1);
    #pragma unroll
    for (int jt = 0; jt < 4; ++jt) {
      floatx4 a0 = {0.f, 0.f, 0.f, 0.f}, a1 = {0.f, 0.f, 0.f, 0.f};
      #pragma unroll
      for (int kc = 0; kc < 4; ++kc) {
        int kr = jt * 16 + l16;
        short8 kb = *(const short8*)&Ks[(kr * 256 + kc * 64 + quad * 16) ^ ((kr & 7) << 4)];
        a0 = __builtin_amdgcn_mfma_f32_16x16x32_f16(
            __builtin_bit_cast(half8, kb), __builtin_bit_cast(half8, qa[0][kc]), a0, 0, 0, 0);
        a1 = __builtin_amdgcn_mfma_f32_16x16x32_f16(
            __builtin_bit_cast(half8, kb), __builtin_bit_cast(half8, qa[1][kc]), a1, 0, 0, 0);
      }
      #pragma unroll
      for (int r = 0; r < 4; ++r) { sreg[0][jt][r] = a0[r]; sreg[1][jt][r] = a1[r]; }
    }
    __builtin_amdgcn_s_setprio(0);

    // per-lane online softmax (exp2 domain); T13 defer-rescale; cvt_pkrtz packing
    float alpha[2]; int need[2];
    #pragma unroll
    for (int f = 0; f < 2; ++f) {
      float mx = sreg[f][0][0];
      #pragma unroll
      for (int jt = 0; jt < 4; ++jt)
        #pragma unroll
        for (int r = 0; r < 4; ++r) mx = fmaxf(mx, sreg[f][jt][r]);
      mx = fmaxf(mx, __shfl_xor(mx, 16));
      mx = fmaxf(mx, __shfl_xor(mx, 32));
      need[f] = !__all(mx <= m_q[f] + 8.f);   // wave-uniform
      float mnew;
      if (need[f]) {
        mnew = fmaxf(m_q[f], mx);
        alpha[f] = exp2f(m_q[f] - mnew);
        m_q[f] = mnew;
      } else {
        mnew = m_q[f];
        alpha[f] = 1.f;
      }
      float ssum = 0.f;
      #pragma unroll
      for (int jt = 0; jt < 4; ++jt) {
        float p0 = exp2f(sreg[f][jt][0] - mnew);
        float p1 = exp2f(sreg[f][jt][1] - mnew);
        float p2 = exp2f(sreg[f][jt][2] - mnew);
        float p3 = exp2f(sreg[f][jt][3] - mnew);
        uint2 pk2;
        pk2.x = pkh2(p0, p1);
        pk2.y = pkh2(p2, p3);
        ssum += (p0 + p1) + (p2 + p3);
        *(uint2*)&Ps[w][((f * 16 + l16) * 128 + jt * 32 + quad * 8) ^ ((l16 & 7) << 4)] = pk2;
      }
      ssum += __shfl_xor(ssum, 16);
      ssum += __shfl_xor(ssum, 32);
      l_q[f] = l_q[f] * alpha[f] + ssum;
    }
    if (need[0]) {
      #pragma unroll
      for (int dt = 0; dt < 8; ++dt)
        #pragma unroll
        for (int r = 0; r < 4; ++r) accO0[dt][r] *= alpha[0];
    }
    if (need[1]) {
      #pragma unroll
      for (int dt = 0; dt < 8; ++dt)
        #pragma unroll
        for (int r = 0; r < 4; ++r) accO1[dt][r] *= alpha[1];
    }

    // O^T = O^T + V^T P^T : vf read once, used by both fragments
    __builtin_amdgcn_s_setprio(1);
    #pragma unroll
    for (int kc = 0; kc < 2; ++kc) {
      short8 pf0 = *(const short8*)&Ps[w][(l16 * 128 + kc * 64 + quad * 16) ^ ((l16 & 7) << 4)];
      short8 pf1 = *(const short8*)&Ps[w][((16 + l16) * 128 + kc * 64 + quad * 16) ^ ((l16 & 7) << 4)];
      #pragma unroll
      for (int dt = 0; dt < 8; ++dt) {
        int vr = dt * 16 + l16;
        short8 vf = *(const short8*)&Vs[(vr * 128 + kc * 64 + quad * 16) ^ ((vr & 7) << 4)];
        accO0[dt] = __builtin_amdgcn_mfma_f32_16x16x32_f16(
            __builtin_bit_cast(half8, vf), __builtin_bit_cast(half8, pf0), accO0[dt], 0, 0, 0);
        accO1[dt] = __builtin_amdgcn_mfma_f32_16x16x32_f16(
            __builtin_bit_cast(half8, vf), __builtin_bit_cast(half8, pf1), accO1[dt], 0, 0, 0);
      }
    }
    __builtin_amdgcn_s_setprio(0);
  }

  // epilogue: fp16 normalized partial O + logsumexp per q-row
  unsigned short* po = half ? po1 : po0;
  #pragma unroll
  for (int f = 0; f < 2; ++f) {
    float invl = 1.0f / l_q[f];
    const size_t qrow = (size_t)(b * SEQ + qt * 128 + w * 32 + f * 16 + l16);
    if (quad == 0)
      lm[(size_t)half * NROWS * HEADS + qrow * HEADS + h] = m_q[f] + log2f(l_q[f]);
    const size_t obase = qrow * DIM + h * HDIM;
    #pragma unroll
    for (int dt = 0; dt < 8; ++dt) {
      floatx4 acc = f == 0 ? accO0[dt] : accO1[dt];
      ushort4 ov;
      ov.x = f2h(acc[0] * invl); ov.y = f2h(acc[1] * invl);
      ov.z = f2h(acc[2] * invl); ov.w = f2h(acc[3] * invl);
      *(ushort4*)(po + obase + dt * 16 + quad * 4) = ov;
    }
  }
}

// ---------------- host ----------------
extern "C" void kernel_launch(void* const* d_in, const int* in_sizes, int n_in,
                              void* d_out, int out_size, void* d_ws, size_t ws_size,
                              hipStream_t stream)
{
  (void)in_sizes; (void)n_in; (void)out_size; (void)ws_size;
  const float* x = (const float*)d_in[0];
  const float* w[4]; const float* g[4]; const float* bb[4];
  for (int i = 0; i < 4; ++i) {
    w[i]  = (const float*)d_in[1 + 3 * i];
    g[i]  = (const float*)d_in[2 + 3 * i];
    bb[i] = (const float*)d_in[3 + 3 * i];
  }

  char* base = (char*)d_ws;
  size_t off = 0;
  auto alloc = [&](size_t bytes) {
    char* p = base + off;
    off += (bytes + 255) & ~(size_t)255;
    return p;
  };
  const size_t ACTH = (size_t)NROWS * DIM * 2;  // 16-bit activation buffer (16 MB)
  const size_t ACT8 = (size_t)NROWS * DIM;      // 8-bit activation buffer (8 MB)
  float* stats          = (float*)alloc(64);
  float* part1          = (float*)alloc(4 * 1024 * sizeof(float));
  float* part2          = (float*)alloc(4 * 1024 * 2 * sizeof(float));
  float* pmax           = (float*)alloc((size_t)4 * NROWS * sizeof(float));
  float* lm             = (float*)alloc((size_t)2 * NROWS * HEADS * sizeof(float));
  signed char* tern     = (signed char*)alloc((size_t)4 * WN);
  signed char* xq0      = (signed char*)alloc(ACT8);
  signed char* xq1      = (signed char*)alloc(ACT8);
  signed char* xq2      = (signed char*)alloc(ACT8);
  unsigned short* qh    = (unsigned short*)alloc(ACTH);
  unsigned short* kh    = (unsigned short*)alloc(ACTH);
  unsigned short* vtb   = (unsigned short*)alloc(ACTH);
  unsigned short* po0   = (unsigned short*)alloc(ACTH);
  unsigned short* po1   = (unsigned short*)alloc(ACTH);
  signed char* xqo = xq0;              // overlay: xq0 dead after the q GEMM
  unsigned* ambits = (unsigned*)(stats + 8);

  hipMemsetAsync(stats, 0, 64, stream);

  dim3 b256(256);
  w_abs_partial<<<dim3(1024, 4), b256, 0, stream>>>(w[0], w[1], w[2], w[3], part1);
  w_delta_final<<<4, b256, 0, stream>>>(part1, stats);
  w_maskquant<<<dim3(1024, 4), b256, 0, stream>>>(w[0], w[1], w[2], w[3], stats, part2, tern);
  w_alpha_final<<<4, b256, 0, stream>>>(part2, stats);

  ln_absmax3<<<NROWS / 4, b256, 0, stream>>>(x, g[0], bb[0], g[1], bb[1], g[2], bb[2], pmax);
  absmax_final<<<3, b256, 0, stream>>>(pmax, ambits);
  ln_quant3<<<NROWS / 4, b256, 0, stream>>>(x, g[0], bb[0], g[1], bb[1], g[2], bb[2], ambits,
                                            xq0, xq1, xq2);

  gemm_qkv<<<dim3(NROWS / 128, DIM / 128, 3), b256, 0, stream>>>(
      xq0, xq1, xq2, tern, qh, kh, vtb, stats);

  flash_attn<<<dim3(32 * 32), b256, 0, stream>>>(qh, kh, vtb, po0, po1, lm);

  ln_kernel<0><<<NROWS / 4, b256, 0, stream>>>(po0, po1, lm, g[3], bb[3], nullptr,
                                               pmax + (size_t)3 * NROWS, nullptr);
  absmax_final<<<1, b256, 0, stream>>>(pmax + (size_t)3 * NROWS, ambits + 3);
  ln_kernel<1><<<NROWS / 4, b256, 0, stream>>>(po0, po1, lm, g[3], bb[3], ambits + 3,
                                               nullptr, xqo);
  gemm_bt<<<dim3(NROWS / 128, DIM / 128), b256, 0, stream>>>(
      xqo, tern + (size_t)3 * WN, (float*)d_out, stats, 3);
}

// Round 13
// 415.986 us; speedup vs baseline: 1.4037x; 1.4037x over previous
//
#include <hip/hip_runtime.h>
#include <math.h>

#define DIM 2048
#define NROWS 4096            // B*S
#define WN (DIM*DIM)
#define HEADS 16
#define HDIM 128
#define SEQ 2048

typedef __attribute__((ext_vector_type(8))) short short8;
typedef __attribute__((ext_vector_type(8))) _Float16 half8;
typedef __attribute__((ext_vector_type(4))) float floatx4;
typedef __attribute__((ext_vector_type(4))) int intx4;

__device__ __forceinline__ unsigned short f2h(float f) {
  _Float16 h = (_Float16)f;
  return __builtin_bit_cast(unsigned short, h);
}
__device__ __forceinline__ float h2f(unsigned short u) {
  _Float16 h = __builtin_bit_cast(_Float16, u);
  return (float)h;
}
// packed f32x2 -> f16x2 (RTZ) as a single u32
__device__ __forceinline__ unsigned pkh2(float a, float b) {
  return __builtin_bit_cast(unsigned, __builtin_amdgcn_cvt_pkrtz(a, b));
}

// async global->LDS, 16B per lane; lds base must be wave-uniform (HW scatters lane i at +i*16)
__device__ __forceinline__ void gload_lds16(const void* g, void* l) {
  __builtin_amdgcn_global_load_lds(
      (const __attribute__((address_space(1))) unsigned int*)g,
      (__attribute__((address_space(3))) unsigned int*)l, 16, 0, 0);
}

__device__ __forceinline__ float wredSum(float v) {
  #pragma unroll
  for (int o = 1; o < 64; o <<= 1) v += __shfl_xor(v, o);
  return v;
}
__device__ __forceinline__ float wredMax(float v) {
  #pragma unroll
  for (int o = 1; o < 64; o <<= 1) v = fmaxf(v, __shfl_xor(v, o));
  return v;
}

__device__ __forceinline__ float blockReduceSum(float v, float* red) {
  int tid = threadIdx.x;
  red[tid] = v; __syncthreads();
  for (int s = 128; s > 0; s >>= 1) {
    if (tid < s) red[tid] += red[tid + s];
    __syncthreads();
  }
  float r = red[0]; __syncthreads();
  return r;
}

__device__ __forceinline__ const float* pick_w(const float* a, const float* b,
                                               const float* c, const float* d, int i) {
  return i == 0 ? a : i == 1 ? b : i == 2 ? c : d;
}

// ---------------- weight stats ----------------
__global__ __launch_bounds__(256) void w_abs_partial(
    const float* w0, const float* w1, const float* w2, const float* w3, float* part)
{
  const float4* w4 = (const float4*)pick_w(w0, w1, w2, w3, blockIdx.y);
  float s = 0.f;
  for (int i = blockIdx.x * 256 + threadIdx.x; i < WN / 4; i += 1024 * 256) {
    float4 v = w4[i];
    s += fabsf(v.x) + fabsf(v.y) + fabsf(v.z) + fabsf(v.w);
  }
  __shared__ float red[256];
  float t = blockReduceSum(s, red);
  if (threadIdx.x == 0) part[blockIdx.y * 1024 + blockIdx.x] = t;
}

__global__ __launch_bounds__(256) void w_delta_final(const float* part, float* stats)
{
  float s = 0.f;
  for (int i = threadIdx.x; i < 1024; i += 256) s += part[blockIdx.x * 1024 + i];
  __shared__ float red[256];
  float t = blockReduceSum(s, red);
  if (threadIdx.x == 0) stats[blockIdx.x] = 0.7f * (t / (float)WN);
}

__device__ __forceinline__ signed char tq(float v, float delta) {
  if (fabsf(v) > delta) return (v > 0.f) ? (signed char)1 : (signed char)-1;
  return (signed char)0;
}

// fused: ternary-quantize weights (int8 {-1,0,1}) AND accumulate alpha partials
__global__ __launch_bounds__(256) void w_maskquant(
    const float* w0, const float* w1, const float* w2, const float* w3,
    const float* stats, float* part2, signed char* tern)
{
  int wi = blockIdx.y;
  const float4* w4 = (const float4*)pick_w(w0, w1, w2, w3, wi);
  float delta = stats[wi];
  char4* out = (char4*)(tern + (size_t)wi * WN);
  float s = 0.f, cnt = 0.f;
  for (int i = blockIdx.x * 256 + threadIdx.x; i < WN / 4; i += 1024 * 256) {
    float4 v = w4[i];
    char4 o;
    float a;
    a = fabsf(v.x); if (a > delta) { s += a; cnt += 1.f; } o.x = tq(v.x, delta);
    a = fabsf(v.y); if (a > delta) { s += a; cnt += 1.f; } o.y = tq(v.y, delta);
    a = fabsf(v.z); if (a > delta) { s += a; cnt += 1.f; } o.z = tq(v.z, delta);
    a = fabsf(v.w); if (a > delta) { s += a; cnt += 1.f; } o.w = tq(v.w, delta);
    out[i] = o;
  }
  __shared__ float red[256];
  float ts = blockReduceSum(s, red);
  float tc = blockReduceSum(cnt, red);
  if (threadIdx.x == 0) {
    part2[((size_t)blockIdx.y * 1024 + blockIdx.x) * 2]     = ts;
    part2[((size_t)blockIdx.y * 1024 + blockIdx.x) * 2 + 1] = tc;
  }
}

__global__ __launch_bounds__(256) void w_alpha_final(const float* part2, float* stats)
{
  float s = 0.f, c = 0.f;
  for (int i = threadIdx.x; i < 1024; i += 256) {
    s += part2[((size_t)blockIdx.x * 1024 + i) * 2];
    c += part2[((size_t)blockIdx.x * 1024 + i) * 2 + 1];
  }
  __shared__ float red[256];
  float ts = blockReduceSum(s, red);
  float tc = blockReduceSum(c, red);
  if (threadIdx.x == 0) stats[4 + blockIdx.x] = ts / fmaxf(tc, 1.f);
}

// ---------------- LN kernels: one WAVE per row, shuffle-only reductions, no atomics --------
__global__ __launch_bounds__(256) void ln_absmax3(
    const float* __restrict__ x,
    const float* __restrict__ g0, const float* __restrict__ b0,
    const float* __restrict__ g1, const float* __restrict__ b1,
    const float* __restrict__ g2, const float* __restrict__ b2,
    float* __restrict__ pmax)     // [3][NROWS] per-row maxima
{
  const int lane = threadIdx.x & 63;
  const int row = blockIdx.x * 4 + (threadIdx.x >> 6);
  const float* xr = x + (size_t)row * DIM;
  float4 a[8];
  float s = 0.f, sq = 0.f;
  #pragma unroll
  for (int j = 0; j < 8; ++j) {
    a[j] = *(const float4*)(xr + j * 256 + lane * 4);
    s  += a[j].x + a[j].y + a[j].z + a[j].w;
    sq += a[j].x*a[j].x + a[j].y*a[j].y + a[j].z*a[j].z + a[j].w*a[j].w;
  }
  s = wredSum(s); sq = wredSum(sq);
  float mu = s * (1.f / DIM);
  float var = sq * (1.f / DIM) - mu * mu;
  float rstd = 1.f / sqrtf(var + 1e-5f);
  const float* gs[3] = {g0, g1, g2};
  const float* bs[3] = {b0, b1, b2};
  #pragma unroll
  for (int p = 0; p < 3; ++p) {
    float m = 0.f;
    #pragma unroll
    for (int j = 0; j < 8; ++j) {
      float4 gg = *(const float4*)(gs[p] + j * 256 + lane * 4);
      float4 bb = *(const float4*)(bs[p] + j * 256 + lane * 4);
      m = fmaxf(m, fabsf((a[j].x - mu) * rstd * gg.x + bb.x));
      m = fmaxf(m, fabsf((a[j].y - mu) * rstd * gg.y + bb.y));
      m = fmaxf(m, fabsf((a[j].z - mu) * rstd * gg.z + bb.z));
      m = fmaxf(m, fabsf((a[j].w - mu) * rstd * gg.w + bb.w));
    }
    m = wredMax(m);
    if (lane == 0) pmax[(size_t)p * NROWS + row] = m;
  }
}

// one block per projection: reduce NROWS partial maxima -> ambits[p] (direct write, no atomic)
__global__ __launch_bounds__(256) void absmax_final(
    const float* __restrict__ pmax, unsigned* __restrict__ ambits)
{
  const float* src = pmax + (size_t)blockIdx.x * NROWS;
  float m = 0.f;
  for (int i = threadIdx.x; i < NROWS; i += 256) m = fmaxf(m, src[i]);
  m = wredMax(m);
  __shared__ float red[4];
  if ((threadIdx.x & 63) == 0) red[threadIdx.x >> 6] = m;
  __syncthreads();
  if (threadIdx.x == 0)
    ambits[blockIdx.x] = __float_as_uint(fmaxf(fmaxf(red[0], red[1]), fmaxf(red[2], red[3])));
}

__global__ __launch_bounds__(256) void ln_quant3(
    const float* __restrict__ x,
    const float* __restrict__ g0, const float* __restrict__ b0,
    const float* __restrict__ g1, const float* __restrict__ b1,
    const float* __restrict__ g2, const float* __restrict__ b2,
    const unsigned* __restrict__ ambits,
    signed char* __restrict__ xq0, signed char* __restrict__ xq1,
    signed char* __restrict__ xq2)
{
  const int lane = threadIdx.x & 63;
  const int row = blockIdx.x * 4 + (threadIdx.x >> 6);
  const float* xr = x + (size_t)row * DIM;
  float4 a[8];
  float s = 0.f, sq = 0.f;
  #pragma unroll
  for (int j = 0; j < 8; ++j) {
    a[j] = *(const float4*)(xr + j * 256 + lane * 4);
    s  += a[j].x + a[j].y + a[j].z + a[j].w;
    sq += a[j].x*a[j].x + a[j].y*a[j].y + a[j].z*a[j].z + a[j].w*a[j].w;
  }
  s = wredSum(s); sq = wredSum(sq);
  float mu = s * (1.f / DIM);
  float var = sq * (1.f / DIM) - mu * mu;
  float rstd = 1.f / sqrtf(var + 1e-5f);
  const float* gs[3] = {g0, g1, g2};
  const float* bs[3] = {b0, b1, b2};
  signed char* outs[3] = {xq0, xq1, xq2};
  #pragma unroll
  for (int p = 0; p < 3; ++p) {
    float sc = 127.f / fmaxf(__uint_as_float(ambits[p]), 1e-5f);
    #pragma unroll
    for (int j = 0; j < 8; ++j) {
      float4 gg = *(const float4*)(gs[p] + j * 256 + lane * 4);
      float4 bb = *(const float4*)(bs[p] + j * 256 + lane * 4);
      float y0 = (a[j].x - mu) * rstd * gg.x + bb.x;
      float y1 = (a[j].y - mu) * rstd * gg.y + bb.y;
      float y2 = (a[j].z - mu) * rstd * gg.z + bb.z;
      float y3 = (a[j].w - mu) * rstd * gg.w + bb.w;
      char4 q;
      q.x = (signed char)(int)fminf(fmaxf(rintf(y0 * sc), -128.f), 127.f);
      q.y = (signed char)(int)fminf(fmaxf(rintf(y1 * sc), -128.f), 127.f);
      q.z = (signed char)(int)fminf(fmaxf(rintf(y2 * sc), -128.f), 127.f);
      q.w = (signed char)(int)fminf(fmaxf(rintf(y3 * sc), -128.f), 127.f);
      *(char4*)(outs[p] + (size_t)row * DIM + j * 256 + lane * 4) = q;
    }
  }
}

// ---------------- single-tensor LN (o projection), wave-per-row ----------------
template<int MODE>
__global__ __launch_bounds__(256) void ln_kernel(
    const float* __restrict__ x, const float* __restrict__ g, const float* __restrict__ bias,
    const unsigned* __restrict__ ambits, float* __restrict__ pmax,
    signed char* __restrict__ xq)
{
  const int lane = threadIdx.x & 63;
  const int row = blockIdx.x * 4 + (threadIdx.x >> 6);
  const float* xr = x + (size_t)row * DIM;
  float4 a[8];
  float s = 0.f, sq = 0.f;
  #pragma unroll
  for (int j = 0; j < 8; ++j) {
    a[j] = *(const float4*)(xr + j * 256 + lane * 4);
    s  += a[j].x + a[j].y + a[j].z + a[j].w;
    sq += a[j].x*a[j].x + a[j].y*a[j].y + a[j].z*a[j].z + a[j].w*a[j].w;
  }
  s = wredSum(s); sq = wredSum(sq);
  float mu = s * (1.f / DIM);
  float var = sq * (1.f / DIM) - mu * mu;
  float rstd = 1.f / sqrtf(var + 1e-5f);
  if (MODE == 0) {
    float m = 0.f;
    #pragma unroll
    for (int j = 0; j < 8; ++j) {
      float4 gg = *(const float4*)(g + j * 256 + lane * 4);
      float4 bb = *(const float4*)(bias + j * 256 + lane * 4);
      m = fmaxf(m, fabsf((a[j].x - mu) * rstd * gg.x + bb.x));
      m = fmaxf(m, fabsf((a[j].y - mu) * rstd * gg.y + bb.y));
      m = fmaxf(m, fabsf((a[j].z - mu) * rstd * gg.z + bb.z));
      m = fmaxf(m, fabsf((a[j].w - mu) * rstd * gg.w + bb.w));
    }
    m = wredMax(m);
    if (lane == 0) pmax[row] = m;
  } else {
    float sc = 127.f / fmaxf(__uint_as_float(*ambits), 1e-5f);
    #pragma unroll
    for (int j = 0; j < 8; ++j) {
      float4 gg = *(const float4*)(g + j * 256 + lane * 4);
      float4 bb = *(const float4*)(bias + j * 256 + lane * 4);
      float y0 = (a[j].x - mu) * rstd * gg.x + bb.x;
      float y1 = (a[j].y - mu) * rstd * gg.y + bb.y;
      float y2 = (a[j].z - mu) * rstd * gg.z + bb.z;
      float y3 = (a[j].w - mu) * rstd * gg.w + bb.w;
      char4 q;
      q.x = (signed char)(int)fminf(fmaxf(rintf(y0 * sc), -128.f), 127.f);
      q.y = (signed char)(int)fminf(fmaxf(rintf(y1 * sc), -128.f), 127.f);
      q.z = (signed char)(int)fminf(fmaxf(rintf(y2 * sc), -128.f), 127.f);
      q.w = (signed char)(int)fminf(fmaxf(rintf(y3 * sc), -128.f), 127.f);
      *(char4*)(xq + (size_t)row * DIM + j * 256 + lane * 4) = q;
    }
  }
}

// ---------------- merged QKV int8 GEMM (z = projection), m97 structure ----------------
// z==0/1: fp16 C store with FUSED RoPE (angle = head * inv[p]; q also scaled by
// (1/sqrt(128))*log2(e)). z==2: transposed fp16 epilogue via LDS -> vt layout.
__global__ __launch_bounds__(256) void gemm_qkv(
    const signed char* __restrict__ A0, const signed char* __restrict__ A1,
    const signed char* __restrict__ A2, const signed char* __restrict__ Bt0,
    unsigned short* __restrict__ C0, unsigned short* __restrict__ C1,
    unsigned short* __restrict__ C2t, const float* __restrict__ stats)
{
  const int tid = threadIdx.x;
  const int lane = tid & 63;
  const int w = tid >> 6;
  const int wm = w >> 1, wn = w & 1;
  const int quad = lane >> 4, l16 = lane & 15;
  const int bm = blockIdx.x * 128, bn = blockIdx.y * 128;
  const int z = blockIdx.z;

  const signed char* A  = z == 0 ? A0 : z == 1 ? A1 : A2;
  const signed char* Bt = Bt0 + (size_t)z * WN;

  // single 32 KB staging buffer (As | Bs); reused by the transposed epilogue for z==2
  __shared__ __align__(16) signed char smem[2 * 128 * 128];
  signed char* As = smem;
  signed char* Bs = smem + 128 * 128;

  const int srow_off = lane >> 3;        // 0..7
  const int scol     = (lane & 7) * 16;  // bytes

  intx4 acc[4][4];
  #pragma unroll
  for (int i = 0; i < 4; ++i)
    #pragma unroll
    for (int j = 0; j < 4; ++j) acc[i][j] = {0, 0, 0, 0};

  for (int k0 = 0; k0 < DIM; k0 += 128) {
    #pragma unroll
    for (int i = 0; i < 4; ++i) {
      int c = i * 4 + w;                 // wave-uniform chunk id, 16 chunks = 128 rows
      int row = c * 8 + srow_off;
      gload_lds16(A  + (size_t)(bm + row) * DIM + k0 + scol, &As[c * 1024]);
      gload_lds16(Bt + (size_t)(bn + row) * DIM + k0 + scol, &Bs[c * 1024]);
    }
    __syncthreads();
    #pragma unroll
    for (int kc = 0; kc < 2; ++kc) {
      intx4 af[4], bf[4];
      #pragma unroll
      for (int i = 0; i < 4; ++i)
        af[i] = *(const intx4*)&As[(wm * 64 + i * 16 + l16) * 128 + kc * 64 + quad * 16];
      #pragma unroll
      for (int j = 0; j < 4; ++j)
        bf[j] = *(const intx4*)&Bs[(wn * 64 + j * 16 + l16) * 128 + kc * 64 + quad * 16];
      #pragma unroll
      for (int i = 0; i < 4; ++i)
        #pragma unroll
        for (int j = 0; j < 4; ++j)
          acc[i][j] = __builtin_amdgcn_mfma_i32_16x16x64_i8(af[i], bf[j], acc[i][j], 0, 0, 0);
    }
    __syncthreads();
  }

  const unsigned* am = (const unsigned*)(stats + 8);
  float scale = stats[4 + z] * fmaxf(__uint_as_float(am[z]), 1e-5f) * (1.f / 127.f);

  if (z < 2) {
    // fused RoPE: head h = blockIdx.y; pair p = d>>1, d = wn*64 + j*16 + l16.
    // even d: v' = v*cs - pv*sn ; odd d: v' = pv*sn + v*cs (pv = partner via shfl_xor 1).
    // q (z==0) folds SC = (1/sqrt(128))*log2(e) into cs/sn.
    const float SC = 0.12751741769011063f;
    const int hh = blockIdx.y;
    const int odd = l16 & 1;
    float cs[4], sn[4];
    #pragma unroll
    for (int j = 0; j < 4; ++j) {
      int p = (wn * 64 + j * 16 + l16) >> 1;
      float inv = exp2f((float)p * -0.20762050593046f);  // 10000^(-p/64)
      float ang = (float)hh * inv;
      float ss, cc;
      __sincosf(ang, &ss, &cc);
      if (z == 0) { ss *= SC; cc *= SC; }
      cs[j] = cc; sn[j] = ss;
    }
    unsigned short* Cp = z == 0 ? C0 : C1;
    #pragma unroll
    for (int i = 0; i < 4; ++i)
      #pragma unroll
      for (int j = 0; j < 4; ++j)
        #pragma unroll
        for (int r = 0; r < 4; ++r) {
          int m = bm + wm * 64 + i * 16 + quad * 4 + r;
          int n = bn + wn * 64 + j * 16 + l16;
          float v = (float)acc[i][j][r] * scale;
          float pv = __shfl_xor(v, 1);
          float out = odd ? (pv * sn[j] + v * cs[j]) : (v * cs[j] - pv * sn[j]);
          Cp[(size_t)m * DIM + n] = f2h(out);
        }
  } else {
    // transposed epilogue: smem := tileT[d][s] fp16, XOR-swizzled; then coalesced store
    #pragma unroll
    for (int i = 0; i < 4; ++i)
      #pragma unroll
      for (int j = 0; j < 4; ++j)
        #pragma unroll
        for (int r = 0; r < 4; ++r) {
          int s = wm * 64 + i * 16 + quad * 4 + r;   // local m (= seq)
          int d = wn * 64 + j * 16 + l16;            // local n (= head dim)
          int byte = (d * 256 + s * 2) ^ ((d & 7) << 4);
          *(unsigned short*)(smem + byte) = f2h((float)acc[i][j][r] * scale);
        }
    __syncthreads();
    const int b = bm >> 11;                // batch (SEQ = 2048 rows per batch)
    const int s_base = bm & (SEQ - 1);
    const int h = blockIdx.y;              // bn covers exactly one head (128 cols)
    const int sc = (tid & 15) * 8;         // halves within a d-row
    #pragma unroll
    for (int pass = 0; pass < 8; ++pass) {
      int d = (tid >> 4) + pass * 16;
      int byte = (d * 256 + sc * 2) ^ ((d & 7) << 4);
      *(uint4*)(C2t + ((size_t)(b * HEADS + h) * HDIM + d) * SEQ + s_base + sc) =
          *(const uint4*)(smem + byte);
    }
  }
}

// ---------------- O-projection int8 GEMM (fp32 out), m97 structure ----------------
__global__ __launch_bounds__(256) void gemm_bt(
    const signed char* __restrict__ A, const signed char* __restrict__ Bt,
    float* __restrict__ Cp, const float* __restrict__ stats, int wi)
{
  const int tid = threadIdx.x;
  const int lane = tid & 63;
  const int w = tid >> 6;
  const int wm = w >> 1, wn = w & 1;
  const int quad = lane >> 4, l16 = lane & 15;
  const int bm = blockIdx.x * 128, bn = blockIdx.y * 128;

  __shared__ __align__(16) signed char As[128 * 128];
  __shared__ __align__(16) signed char Bs[128 * 128];

  const int srow_off = lane >> 3;
  const int scol     = (lane & 7) * 16;

  intx4 acc[4][4];
  #pragma unroll
  for (int i = 0; i < 4; ++i)
    #pragma unroll
    for (int j = 0; j < 4; ++j) acc[i][j] = {0, 0, 0, 0};

  for (int k0 = 0; k0 < DIM; k0 += 128) {
    #pragma unroll
    for (int i = 0; i < 4; ++i) {
      int c = i * 4 + w;
      int row = c * 8 + srow_off;
      gload_lds16(A  + (size_t)(bm + row) * DIM + k0 + scol, &As[c * 1024]);
      gload_lds16(Bt + (size_t)(bn + row) * DIM + k0 + scol, &Bs[c * 1024]);
    }
    __syncthreads();
    #pragma unroll
    for (int kc = 0; kc < 2; ++kc) {
      intx4 af[4], bf[4];
      #pragma unroll
      for (int i = 0; i < 4; ++i)
        af[i] = *(const intx4*)&As[(wm * 64 + i * 16 + l16) * 128 + kc * 64 + quad * 16];
      #pragma unroll
      for (int j = 0; j < 4; ++j)
        bf[j] = *(const intx4*)&Bs[(wn * 64 + j * 16 + l16) * 128 + kc * 64 + quad * 16];
      #pragma unroll
      for (int i = 0; i < 4; ++i)
        #pragma unroll
        for (int j = 0; j < 4; ++j)
          acc[i][j] = __builtin_amdgcn_mfma_i32_16x16x64_i8(af[i], bf[j], acc[i][j], 0, 0, 0);
    }
    __syncthreads();
  }

  const unsigned* am = (const unsigned*)(stats + 8);
  float scale = stats[4 + wi] * fmaxf(__uint_as_float(am[wi]), 1e-5f) * (1.f / 127.f);
  #pragma unroll
  for (int i = 0; i < 4; ++i)
    #pragma unroll
    for (int j = 0; j < 4; ++j)
      #pragma unroll
      for (int r = 0; r < 4; ++r) {
        int m = bm + wm * 64 + i * 16 + quad * 4 + r;
        int n = bn + wn * 64 + j * 16 + l16;
        Cp[(size_t)m * DIM + n] = (float)acc[i][j][r] * scale;
      }
}

// ---------------- flash attention: QBLK=128 (2 Q-fragments/wave), gload_lds staging -------
// Q pre-scaled by (1/sqrt(128))*log2(e); softmax in exp2 domain; T13 defer-rescale.
// Staging cost (8 gloads + vmcnt(0) + 2 barriers per 64-key tile) amortized over 2x MFMA.
// global_load_lds DMA with PRE-SWIZZLED global source addresses (rule #21).
// XCD-chunked remap: id%8 = XCD, 4 bh/XCD. Grid 512 = 2 blocks/CU; LDS 48KB.
__global__ __launch_bounds__(256, 2) void flash_attn(
    const unsigned short* __restrict__ qf, const unsigned short* __restrict__ kf,
    const unsigned short* __restrict__ vt, float* __restrict__ o)
{
  const int tid = threadIdx.x;
  const int lane = tid & 63;
  const int w = tid >> 6;
  const int quad = lane >> 4;
  const int l16 = lane & 15;
  // XCD-chunked decode: xcd = id&7, slot = id>>3; bh = xcd*4 + slot/16, qt = slot%16
  const int L = blockIdx.x;
  const int slot = L >> 3;
  const int bh = ((L & 7) << 2) | (slot >> 4);
  const int qt = slot & 15;
  const int b = bh >> 4;
  const int h = bh & 15;

  __shared__ __align__(16) char Ks[64 * 256];     // [key t][d] halves; swizzled via source
  __shared__ __align__(16) char Vs[128 * 128];    // [d][t] halves;    swizzled via source
  __shared__ __align__(16) char Ps[4][32 * 128];  // per-wave [q 0..31][t] halves, swizzled

  // Q fragments (B-operand): wave owns 32 q-rows, two 16-row fragments
  const size_t qbase = ((size_t)(b * SEQ + qt * 128 + w * 32 + l16)) * DIM + h * HDIM;
  short8 qa[2][4];
  #pragma unroll
  for (int f = 0; f < 2; ++f)
    #pragma unroll
    for (int kc = 0; kc < 4; ++kc)
      qa[f][kc] = *(const short8*)(qf + qbase + (size_t)f * 16 * DIM + kc * 32 + quad * 8);

  float m_q[2] = {-INFINITY, -INFINITY};
  float l_q[2] = {0.f, 0.f};
  floatx4 accO0[8], accO1[8];           // O^T: rows d=dt*16+quad*4+r, col q = f*16+l16
  #pragma unroll
  for (int i = 0; i < 8; ++i) { accO0[i] = {0.f, 0.f, 0.f, 0.f}; accO1[i] = {0.f, 0.f, 0.f, 0.f}; }

  const char* kg = (const char*)(kf + (size_t)(b * SEQ) * DIM + h * HDIM);
  const char* vg = (const char*)(vt + (size_t)bh * HDIM * SEQ);

  // per-lane pre-swizzled source offsets (bytes) for this wave's 4 chunks of K and V.
  int koff[4], voff[4];
  #pragma unroll
  for (int j = 0; j < 4; ++j) {
    int c = w * 4 + j;
    int rK = c * 4 + (lane >> 4);
    koff[j] = rK * (DIM * 2) + (((lane & 15) * 16) ^ ((rK & 7) << 4));
    int rV = c * 8 + (lane >> 3);
    voff[j] = rV * (SEQ * 2) + (((lane & 7) * 16) ^ ((rV & 7) << 4));
  }

  for (int kt = 0; kt < SEQ / 64; ++kt) {
    __syncthreads();                    // prior tile's LDS reads complete
    const char* kgb = kg + (size_t)kt * 64 * DIM * 2;   // key rows advance
    const char* vgb = vg + (size_t)kt * 128;            // value cols advance (bytes)
    #pragma unroll
    for (int j = 0; j < 4; ++j) {
      int c = w * 4 + j;
      gload_lds16(kgb + koff[j], &Ks[c * 1024]);
      gload_lds16(vgb + voff[j], &Vs[c * 1024]);
    }
    asm volatile("s_waitcnt vmcnt(0)" ::: "memory");
    __syncthreads();

    // S^T = K Q'^T : lane q = f*16+l16, keys t = jt*16 + quad*4 + r
    float sreg[2][4][4];
    __builtin_amdgcn_s_setprio(1);
    #pragma unroll
    for (int jt = 0; jt < 4; ++jt) {
      floatx4 a0 = {0.f, 0.f, 0.f, 0.f}, a1 = {0.f, 0.f, 0.f, 0.f};
      #pragma unroll
      for (int kc = 0; kc < 4; ++kc) {
        int kr = jt * 16 + l16;
        short8 kb = *(const short8*)&Ks[(kr * 256 + kc * 64 + quad * 16) ^ ((kr & 7) << 4)];
        a0 = __builtin_amdgcn_mfma_f32_16x16x32_f16(
            __builtin_bit_cast(half8, kb), __builtin_bit_cast(half8, qa[0][kc]), a0, 0, 0, 0);
        a1 = __builtin_amdgcn_mfma_f32_16x16x32_f16(
            __builtin_bit_cast(half8, kb), __builtin_bit_cast(half8, qa[1][kc]), a1, 0, 0, 0);
      }
      #pragma unroll
      for (int r = 0; r < 4; ++r) { sreg[0][jt][r] = a0[r]; sreg[1][jt][r] = a1[r]; }
    }
    __builtin_amdgcn_s_setprio(0);

    // per-lane online softmax (exp2 domain); T13 defer-rescale; cvt_pkrtz packing
    float alpha[2]; int need[2];
    #pragma unroll
    for (int f = 0; f < 2; ++f) {
      float mx = sreg[f][0][0];
      #pragma unroll
      for (int jt = 0; jt < 4; ++jt)
        #pragma unroll
        for (int r = 0; r < 4; ++r) mx = fmaxf(mx, sreg[f][jt][r]);
      mx = fmaxf(mx, __shfl_xor(mx, 16));
      mx = fmaxf(mx, __shfl_xor(mx, 32));
      need[f] = !__all(mx <= m_q[f] + 8.f);   // wave-uniform
      float mnew;
      if (need[f]) {
        mnew = fmaxf(m_q[f], mx);
        alpha[f] = exp2f(m_q[f] - mnew);
        m_q[f] = mnew;
      } else {
        mnew = m_q[f];
        alpha[f] = 1.f;
      }
      float ssum = 0.f;
      #pragma unroll
      for (int jt = 0; jt < 4; ++jt) {
        float p0 = exp2f(sreg[f][jt][0] - mnew);
        float p1 = exp2f(sreg[f][jt][1] - mnew);
        float p2 = exp2f(sreg[f][jt][2] - mnew);
        float p3 = exp2f(sreg[f][jt][3] - mnew);
        uint2 pk2;
        pk2.x = pkh2(p0, p1);
        pk2.y = pkh2(p2, p3);
        ssum += (p0 + p1) + (p2 + p3);
        *(uint2*)&Ps[w][((f * 16 + l16) * 128 + jt * 32 + quad * 8) ^ ((l16 & 7) << 4)] = pk2;
      }
      ssum += __shfl_xor(ssum, 16);
      ssum += __shfl_xor(ssum, 32);
      l_q[f] = l_q[f] * alpha[f] + ssum;
    }
    if (need[0]) {
      #pragma unroll
      for (int dt = 0; dt < 8; ++dt)
        #pragma unroll
        for (int r = 0; r < 4; ++r) accO0[dt][r] *= alpha[0];
    }
    if (need[1]) {
      #pragma unroll
      for (int dt = 0; dt < 8; ++dt)
        #pragma unroll
        for (int r = 0; r < 4; ++r) accO1[dt][r] *= alpha[1];
    }

    // O^T = O^T + V^T P^T : vf read once, used by both fragments
    __builtin_amdgcn_s_setprio(1);
    #pragma unroll
    for (int kc = 0; kc < 2; ++kc) {
      short8 pf0 = *(const short8*)&Ps[w][(l16 * 128 + kc * 64 + quad * 16) ^ ((l16 & 7) << 4)];
      short8 pf1 = *(const short8*)&Ps[w][((16 + l16) * 128 + kc * 64 + quad * 16) ^ ((l16 & 7) << 4)];
      #pragma unroll
      for (int dt = 0; dt < 8; ++dt) {
        int vr = dt * 16 + l16;
        short8 vf = *(const short8*)&Vs[(vr * 128 + kc * 64 + quad * 16) ^ ((vr & 7) << 4)];
        accO0[dt] = __builtin_amdgcn_mfma_f32_16x16x32_f16(
            __builtin_bit_cast(half8, vf), __builtin_bit_cast(half8, pf0), accO0[dt], 0, 0, 0);
        accO1[dt] = __builtin_amdgcn_mfma_f32_16x16x32_f16(
            __builtin_bit_cast(half8, vf), __builtin_bit_cast(half8, pf1), accO1[dt], 0, 0, 0);
      }
    }
    __builtin_amdgcn_s_setprio(0);
  }

  // epilogue: float4 stores, 16B per lane
  #pragma unroll
  for (int f = 0; f < 2; ++f) {
    float invl = 1.0f / l_q[f];
    const size_t obase = (size_t)(b * SEQ + qt * 128 + w * 32 + f * 16 + l16) * DIM + h * HDIM;
    #pragma unroll
    for (int dt = 0; dt < 8; ++dt) {
      floatx4 acc = f == 0 ? accO0[dt] : accO1[dt];
      float4 ov;
      ov.x = acc[0] * invl; ov.y = acc[1] * invl;
      ov.z = acc[2] * invl; ov.w = acc[3] * invl;
      *(float4*)(o + obase + dt * 16 + quad * 4) = ov;
    }
  }
}

// ---------------- host ----------------
extern "C" void kernel_launch(void* const* d_in, const int* in_sizes, int n_in,
                              void* d_out, int out_size, void* d_ws, size_t ws_size,
                              hipStream_t stream)
{
  (void)in_sizes; (void)n_in; (void)out_size; (void)ws_size;
  const float* x = (const float*)d_in[0];
  const float* w[4]; const float* g[4]; const float* bb[4];
  for (int i = 0; i < 4; ++i) {
    w[i]  = (const float*)d_in[1 + 3 * i];
    g[i]  = (const float*)d_in[2 + 3 * i];
    bb[i] = (const float*)d_in[3 + 3 * i];
  }

  char* base = (char*)d_ws;
  size_t off = 0;
  auto alloc = [&](size_t bytes) {
    char* p = base + off;
    off += (bytes + 255) & ~(size_t)255;
    return p;
  };
  const size_t ACTH = (size_t)NROWS * DIM * 2;  // 16-bit activation buffer (16 MB)
  const size_t ACT8 = (size_t)NROWS * DIM;      // 8-bit activation buffer (8 MB)
  float* stats          = (float*)alloc(64);
  float* part1          = (float*)alloc(4 * 1024 * sizeof(float));
  float* part2          = (float*)alloc(4 * 1024 * 2 * sizeof(float));
  float* pmax           = (float*)alloc((size_t)4 * NROWS * sizeof(float));
  signed char* tern     = (signed char*)alloc((size_t)4 * WN);
  signed char* xq0      = (signed char*)alloc(ACT8);
  signed char* xq1      = (signed char*)alloc(ACT8);
  signed char* xq2      = (signed char*)alloc(ACT8);
  unsigned short* qh    = (unsigned short*)alloc(ACTH);
  unsigned short* kh    = (unsigned short*)alloc(ACTH);
  unsigned short* vtb   = (unsigned short*)alloc(ACTH);
  float* oat            = (float*)alloc((size_t)NROWS * DIM * sizeof(float));
  signed char* xqo = xq0;              // overlay: xq0 dead after the q GEMM
  unsigned* ambits = (unsigned*)(stats + 8);

  hipMemsetAsync(stats, 0, 64, stream);

  dim3 b256(256);
  w_abs_partial<<<dim3(1024, 4), b256, 0, stream>>>(w[0], w[1], w[2], w[3], part1);
  w_delta_final<<<4, b256, 0, stream>>>(part1, stats);
  w_maskquant<<<dim3(1024, 4), b256, 0, stream>>>(w[0], w[1], w[2], w[3], stats, part2, tern);
  w_alpha_final<<<4, b256, 0, stream>>>(part2, stats);

  ln_absmax3<<<NROWS / 4, b256, 0, stream>>>(x, g[0], bb[0], g[1], bb[1], g[2], bb[2], pmax);
  absmax_final<<<3, b256, 0, stream>>>(pmax, ambits);
  ln_quant3<<<NROWS / 4, b256, 0, stream>>>(x, g[0], bb[0], g[1], bb[1], g[2], bb[2], ambits,
                                            xq0, xq1, xq2);

  gemm_qkv<<<dim3(NROWS / 128, DIM / 128, 3), b256, 0, stream>>>(
      xq0, xq1, xq2, tern, qh, kh, vtb, stats);

  flash_attn<<<dim3(16 * 32), b256, 0, stream>>>(qh, kh, vtb, oat);

  ln_kernel<0><<<NROWS / 4, b256, 0, stream>>>(oat, g[3], bb[3], nullptr,
                                               pmax + (size_t)3 * NROWS, nullptr);
  absmax_final<<<1, b256, 0, stream>>>(pmax + (size_t)3 * NROWS, ambits + 3);
  ln_kernel<1><<<NROWS / 4, b256, 0, stream>>>(oat, g[3], bb[3], ambits + 3, nullptr, xqo);
  gemm_bt<<<dim3(NROWS / 128, DIM / 128), b256, 0, stream>>>(
      xqo, tern + (size_t)3 * WN, (float*)d_out, stats, 3);
}